// Round 10
// baseline (303.139 us; speedup 1.0000x reference)
//
#include <hip/hip_runtime.h>
#include <math.h>

#define HW 9216          // 96*96
#define WID 96
#define CIN 256
#define COUT 256
#define NTOT 18432       // B*HW
#define KC 2304          // CIN*9
#define NKS 72           // KC/32 k-steps

typedef short bf16x8 __attribute__((ext_vector_type(8)));
typedef float f32x4  __attribute__((ext_vector_type(4)));

__device__ __forceinline__ unsigned short f2bf(float f) {
    union { float f; unsigned int u; } v; v.f = f;
    unsigned int u = v.u;
    return (unsigned short)((u + 0x7fffu + ((u >> 16) & 1u)) >> 16);  // RNE
}
__device__ __forceinline__ float bflo(unsigned u) {
    union { unsigned u; float f; } v; v.u = u << 16; return v.f;
}
__device__ __forceinline__ float bfhi(unsigned u) {
    union { unsigned u; float f; } v; v.u = u & 0xFFFF0000u; return v.f;
}

// ws layout (float offsets) — identical to R8 (fits proven ws budget):
//   off  : 0       .. 331776
//   stats: 331776  .. 331904
//   A'   : 331904  .. 626816   (589824 ushort, fragment-major weights)
//   xt   : 626816  .. 2986112  (bf16 NHWC [b][p][c], 4718592 ushort)
//   B'   : 2986112 ..          (42467328 ushort, fragment-major patches)
//
// Fragment-major layout (16x16x32 MFMA operand order):
//   A'[(((mb*72+ks)*4 + i)*64 + lane)*8 + s] = wbf16[m=mb*64+i*16+(lane&15)][ks*32+(lane>>4)*8+s]
//   B'[(((g *72+ks)*4 + j)*64 + lane)*8 + s] = P    [n=g *64+j*16+(lane&15)][ks*32+(lane>>4)*8+s]

// Prologue: [0,4608) xt bf16 | [4608,5184) A' swizzle | [5184,6480) off init + stats=0
__global__ __launch_bounds__(256) void prelude(const float* __restrict__ x,
                                               unsigned short* __restrict__ xt,
                                               const float* __restrict__ cw,
                                               unsigned short* __restrict__ Aw,
                                               const float* __restrict__ offset_b,
                                               float* __restrict__ off,
                                               float* __restrict__ stats) {
    __shared__ float L[32][33];
    int blk = blockIdx.x, t = threadIdx.x;
    if (blk < 4608) {                       // x NCHW fp32 -> NHWC bf16
        int pt = blk % 288, ct = (blk / 288) & 7, b = blk / 2304;
        int pl = t & 31, ch = t >> 5;
#pragma unroll
        for (int i = 0; i < 4; i++) {
            int cl = ch * 4 + i;
            L[cl][pl] = x[((size_t)(b * CIN + ct * 32 + cl)) * HW + pt * 32 + pl];
        }
        __syncthreads();
        int cc = t & 31;
#pragma unroll
        for (int i = 0; i < 4; i++) {
            int pr = ch * 4 + i;
            xt[((size_t)(b * HW + pt * 32 + pr)) * 256 + ct * 32 + cc] = f2bf(L[cc][pr]);
        }
    } else if (blk < 5184) {                // conv_w -> A' fragment-major bf16
        int tid = (blk - 4608) * 256 + t;   // [0,147456)
        int oc = tid / 576;
        int kc = (tid % 576) * 4;
        int k = kc >> 8, c = kc & 255;
        unsigned short v[4] __attribute__((aligned(8)));
#pragma unroll
        for (int i = 0; i < 4; i++)
            v[i] = f2bf(cw[((size_t)oc * 256 + c + i) * 9 + k]);
        int ks = kc >> 5, quad = (kc >> 3) & 3, sidx = kc & 7;
        int ifr = (oc >> 4) & 3, lane = quad * 16 + (oc & 15);
        size_t flat = (((size_t)((oc >> 6) * 72 + ks) * 4 + ifr) * 64 + lane) * 8 + sidx;
        *(uint2*)(Aw + flat) = *(const uint2*)v;
    } else {                                // off = bias, stats = 0
        int i = (blk - 5184) * 256 + t;
        if (i < 331776) off[i] = offset_b[(i / HW) % 18];
        if (i < 128) stats[i] = 0.f;
    }
}

// 3x3 pad-1 conv -> 18 offset channels (R8-proven). 16 c-chunks x 72 blocks.
__global__ __launch_bounds__(256) void offset_conv(const float* __restrict__ x,
                                                   const float* __restrict__ ow,
                                                   float* __restrict__ off) {
    int chunk = blockIdx.x / 72;
    int pg = (blockIdx.x % 72) * 256 + threadIdx.x;
    int b  = pg / HW;
    int p  = pg % HW;
    int ho = p / WID, wo = p % WID;
    const float* xb = x + (size_t)b * CIN * HW;

    float acc[18];
#pragma unroll
    for (int ch = 0; ch < 18; ch++) acc[ch] = 0.f;

    int c0 = chunk * 16;
    for (int ci = 0; ci < 16; ci++) {
        int c = c0 + ci;
        const float* xc = xb + (size_t)c * HW;
#pragma unroll
        for (int ky = 0; ky < 3; ky++) {
            int y = ho - 1 + ky;
            if (y < 0 || y >= 96) continue;
#pragma unroll
            for (int kx = 0; kx < 3; kx++) {
                int xx = wo - 1 + kx;
                float xv = (xx >= 0 && xx < 96) ? xc[y * WID + xx] : 0.f;
                int widx = c * 9 + ky * 3 + kx;
#pragma unroll
                for (int ch = 0; ch < 18; ch++)
                    acc[ch] += xv * ow[ch * (CIN * 9) + widx];
            }
        }
    }
#pragma unroll
    for (int ch = 0; ch < 18; ch++)
        atomicAdd(&off[((size_t)b * 18 + ch) * HW + p], acc[ch]);
}

// Gather (R8-proven): one wave per n, 9 taps; 4 coalesced 512B bf16 corner-row
// reads per tap; scatter-stores into B' fragment-major layout.
__global__ __launch_bounds__(256) void gather4(const unsigned short* __restrict__ xt,
                                               const float* __restrict__ off,
                                               unsigned short* __restrict__ Bp) {
    int t    = threadIdx.x;
    int w    = t >> 6;
    int lane = t & 63;
    int n    = blockIdx.x * 4 + w;
    int b    = n / HW, p = n % HW;
    int ho   = p / WID, wo = p % WID;
    const unsigned short* xb = xt + (size_t)b * (HW * 256);
    const float* offb = off + (size_t)b * 18 * HW + p;
    int c4 = lane * 4;

    int jfr = (n >> 4) & 3, l15n = n & 15;
    int lhi = lane >> 3, lq = (lane >> 1) & 3, lp = lane & 1;
    size_t gbase = (size_t)(n >> 6) * 72;

#pragma unroll 3
    for (int k = 0; k < 9; k++) {
        int ky = k / 3, kx = k % 3;
        float dy = offb[(size_t)(2 * k)     * HW];
        float dx = offb[(size_t)(2 * k + 1) * HW];
        float sy = (float)(ho - 1 + ky) + dy;
        float sx = (float)(wo - 1 + kx) + dx;
        float y0f = floorf(sy), x0f = floorf(sx);
        float fy = sy - y0f, fx = sx - x0f;
        int y0 = (int)y0f, x0 = (int)x0f;
        int y1 = y0 + 1, x1 = x0 + 1;
        float vy0 = (y0 >= 0 && y0 < 96) ? 1.f : 0.f;
        float vy1 = (y1 >= 0 && y1 < 96) ? 1.f : 0.f;
        float vx0 = (x0 >= 0 && x0 < 96) ? 1.f : 0.f;
        float vx1 = (x1 >= 0 && x1 < 96) ? 1.f : 0.f;
        int iy0 = min(max(y0, 0), 95) * WID, iy1 = min(max(y1, 0), 95) * WID;
        int ix0 = min(max(x0, 0), 95),       ix1 = min(max(x1, 0), 95);
        float w0 = (1.f - fy) * (1.f - fx) * vy0 * vx0;
        float w1 = (1.f - fy) * fx         * vy0 * vx1;
        float w2 = fy         * (1.f - fx) * vy1 * vx0;
        float w3 = fy         * fx         * vy1 * vx1;

        uint2 u0 = *(const uint2*)(xb + (size_t)(iy0 + ix0) * 256 + c4);
        uint2 u1 = *(const uint2*)(xb + (size_t)(iy0 + ix1) * 256 + c4);
        uint2 u2 = *(const uint2*)(xb + (size_t)(iy1 + ix0) * 256 + c4);
        uint2 u3 = *(const uint2*)(xb + (size_t)(iy1 + ix1) * 256 + c4);
        float r0 = w0 * bflo(u0.x) + w1 * bflo(u1.x) + w2 * bflo(u2.x) + w3 * bflo(u3.x);
        float r1 = w0 * bfhi(u0.x) + w1 * bfhi(u1.x) + w2 * bfhi(u2.x) + w3 * bfhi(u3.x);
        float r2 = w0 * bflo(u0.y) + w1 * bflo(u1.y) + w2 * bflo(u2.y) + w3 * bflo(u3.y);
        float r3 = w0 * bfhi(u0.y) + w1 * bfhi(u1.y) + w2 * bfhi(u2.y) + w3 * bfhi(u3.y);
        uint2 o;
        o.x = (unsigned)f2bf(r0) | ((unsigned)f2bf(r1) << 16);
        o.y = (unsigned)f2bf(r2) | ((unsigned)f2bf(r3) << 16);
        size_t ds = (((gbase + k * 8 + lhi) * 4 + jfr) * 64 + lq * 16 + l15n) * 8 + lp * 4;
        *(uint2*)(Bp + ds) = o;
    }
}

// GEMM v5: barrier-free register GEMM, depth-3 ring (R8-proven), but 4-wave
// blocks: 256 thr as 2x2 wave grid, block tile 128M x 64N, wave tile 64M x 32N.
// Grid 576 -> 9 waves/CU (4x R8's concurrency); b-frags shared by wave pairs
// via L1; the two mbh-blocks of a B' tile are 8 ids apart (same XCD slot).
// Per k-step per wave: 4 A + 2 B coalesced dwordx4 loads + 8 MFMA.
__global__ __launch_bounds__(256) void gemm_mfma(const unsigned short* __restrict__ Aw,
                                                 const unsigned short* __restrict__ Bp,
                                                 float* __restrict__ out,
                                                 float* __restrict__ stats) {
    int t    = threadIdx.x;
    int lane = t & 63;
    int w    = t >> 6;
    int wm   = w >> 1, wn = w & 1;
    int l15  = lane & 15, quad = lane >> 4;

    int f   = blockIdx.x;
    int mbh = (f >> 3) & 1;
    int g   = (f & 7) + (f >> 4) * 8;     // [0,288)
    int mb  = mbh * 2 + wm;

    const bf16x8* Ab = (const bf16x8*)Aw + (size_t)mb * 72 * 4 * 64 + lane;
    const bf16x8* Bb = (const bf16x8*)Bp + (size_t)g  * 72 * 4 * 64 + lane;

    f32x4 acc[4][2];
#pragma unroll
    for (int i = 0; i < 4; i++)
#pragma unroll
        for (int j = 0; j < 2; j++) acc[i][j] = (f32x4)0.f;

    bf16x8 a[3][4], b[3][2];

#define LOADSET(s, ks)                                        \
    {                                                         \
        _Pragma("unroll")                                     \
        for (int q = 0; q < 4; q++)                           \
            a[s][q] = Ab[((ks) * 4 + q) * 64];                \
        _Pragma("unroll")                                     \
        for (int q = 0; q < 2; q++)                           \
            b[s][q] = Bb[((ks) * 4 + wn * 2 + q) * 64];       \
    }
#define MFMASET(s)                                                            \
    {                                                                         \
        _Pragma("unroll")                                                     \
        for (int i = 0; i < 4; i++)                                           \
            _Pragma("unroll")                                                 \
            for (int j = 0; j < 2; j++)                                       \
                acc[i][j] = __builtin_amdgcn_mfma_f32_16x16x32_bf16(          \
                    a[s][i], b[s][j], acc[i][j], 0, 0, 0);                    \
    }

    LOADSET(0, 0);
    LOADSET(1, 1);
    LOADSET(2, 2);
    for (int ks = 0; ks < 69; ks += 3) {
        MFMASET(0); LOADSET(0, ks + 3);
        MFMASET(1); LOADSET(1, ks + 4);
        MFMASET(2); LOADSET(2, ks + 5);
    }
    MFMASET(0);     // ks 69
    MFMASET(1);     // ks 70
    MFMASET(2);     // ks 71

    int b_ = g / 144;
    int p0 = (g % 144) * 64;
#pragma unroll
    for (int i = 0; i < 4; i++) {
        int mr = mb * 64 + i * 16 + quad * 4;
        float s = 0.f, ss = 0.f;
#pragma unroll
        for (int j = 0; j < 2; j++) {
            float* ob = out + ((size_t)b_ * COUT + mr) * HW + p0 + (wn * 2 + j) * 16 + l15;
#pragma unroll
            for (int r = 0; r < 4; r++) {
                float v = acc[i][j][r];
                ob[(size_t)r * HW] = v;
                s  += v;
                ss += v * v;
            }
        }
        float sv = s, ssv = ss;
#pragma unroll
        for (int d = 1; d < 32; d <<= 1) {
            sv  += __shfl_xor(sv,  d);
            ssv += __shfl_xor(ssv, d);
        }
        if ((lane & 31) == 0) {
            int bg = b_ * 32 + mb * 8 + i * 2 + (lane >> 5);
            atomicAdd(&stats[bg * 2],     sv);
            atomicAdd(&stats[bg * 2 + 1], ssv);
        }
    }
}

__global__ __launch_bounds__(256) void gn_norm(float* __restrict__ out,
                                               const float* __restrict__ stats,
                                               const float* __restrict__ gamma,
                                               const float* __restrict__ beta) {
    int i4 = blockIdx.x * 256 + threadIdx.x;
    if (i4 >= 1179648) return;
    float4 v = ((const float4*)out)[i4];
    int e  = i4 * 4;
    int ch = (e / HW) & 255;
    int b  = e / (HW * 256);
    int bg = b * 32 + (ch >> 3);
    float s = stats[bg * 2], ss = stats[bg * 2 + 1];
    float mean = s * (1.f / 73728.f);
    float rs   = rsqrtf(ss * (1.f / 73728.f) - mean * mean + 1e-5f);
    float ga = gamma[ch] * rs;
    float be = beta[ch] - mean * ga;
    v.x = fmaxf(v.x * ga + be, 0.f);
    v.y = fmaxf(v.y * ga + be, 0.f);
    v.z = fmaxf(v.z * ga + be, 0.f);
    v.w = fmaxf(v.w * ga + be, 0.f);
    ((float4*)out)[i4] = v;
}

extern "C" void kernel_launch(void* const* d_in, const int* in_sizes, int n_in,
                              void* d_out, int out_size, void* d_ws, size_t ws_size,
                              hipStream_t stream) {
    const float* x        = (const float*)d_in[0];
    const float* offset_w = (const float*)d_in[1];
    const float* offset_b = (const float*)d_in[2];
    const float* conv_w   = (const float*)d_in[3];
    const float* gamma    = (const float*)d_in[4];
    const float* beta     = (const float*)d_in[5];
    float* out = (float*)d_out;
    float* ws  = (float*)d_ws;

    float*          off   = ws;
    float*          stats = ws + 331776;
    unsigned short* Aw    = (unsigned short*)(ws + 331904);
    unsigned short* xt    = (unsigned short*)(ws + 626816);
    unsigned short* Bp    = (unsigned short*)(ws + 2986112);

    hipLaunchKernelGGL(prelude,     dim3(6480), dim3(256), 0, stream,
                       x, xt, conv_w, Aw, offset_b, off, stats);
    hipLaunchKernelGGL(offset_conv, dim3(1152), dim3(256), 0, stream, x, offset_w, off);
    hipLaunchKernelGGL(gather4,     dim3(4608), dim3(256), 0, stream, xt, off, Bp);
    hipLaunchKernelGGL(gemm_mfma,   dim3(576),  dim3(256), 0, stream, Aw, Bp, out, stats);
    hipLaunchKernelGGL(gn_norm,     dim3(4608), dim3(256), 0, stream, out, stats, gamma, beta);
}

// Round 11
// 239.381 us; speedup vs baseline: 1.2663x; 1.2663x over previous
//
#include <hip/hip_runtime.h>
#include <math.h>

#define HW 9216          // 96*96
#define WID 96
#define CIN 256
#define COUT 256
#define NTOT 18432       // B*HW
#define KC 2304          // CIN*9
#define NKS 72           // KC/32 k-steps

typedef short bf16x8 __attribute__((ext_vector_type(8)));
typedef float f32x4  __attribute__((ext_vector_type(4)));

__device__ __forceinline__ unsigned short f2bf(float f) {
    union { float f; unsigned int u; } v; v.f = f;
    unsigned int u = v.u;
    return (unsigned short)((u + 0x7fffu + ((u >> 16) & 1u)) >> 16);  // RNE
}
__device__ __forceinline__ float bflo(unsigned u) {
    union { unsigned u; float f; } v; v.u = u << 16; return v.f;
}
__device__ __forceinline__ float bfhi(unsigned u) {
    union { unsigned u; float f; } v; v.u = u & 0xFFFF0000u; return v.f;
}

// ws layout (float offsets) — identical to R8:
//   off  : 0       .. 331776
//   stats: 331776  .. 331904
//   A'   : 331904  .. 626816   (589824 ushort, fragment-major weights)
//   xt   : 626816  .. 2986112  (bf16 NHWC [b][p][c], 4718592 ushort)
//   B'   : 2986112 ..          (42467328 ushort, fragment-major patches)
//
// Fragment-major layout (16x16x32 MFMA operand order):
//   A'[(((mb*72+ks)*4 + i)*64 + lane)*8 + s] = wbf16[m=mb*64+i*16+(lane&15)][ks*32+(lane>>4)*8+s]
//   B'[(((g *72+ks)*4 + j)*64 + lane)*8 + s] = P    [n=g *64+j*16+(lane&15)][ks*32+(lane>>4)*8+s]

// Prologue: [0,4608) xt bf16 | [4608,5184) A' swizzle | [5184,6480) off init + stats=0
__global__ __launch_bounds__(256) void prelude(const float* __restrict__ x,
                                               unsigned short* __restrict__ xt,
                                               const float* __restrict__ cw,
                                               unsigned short* __restrict__ Aw,
                                               const float* __restrict__ offset_b,
                                               float* __restrict__ off,
                                               float* __restrict__ stats) {
    __shared__ float L[32][33];
    int blk = blockIdx.x, t = threadIdx.x;
    if (blk < 4608) {                       // x NCHW fp32 -> NHWC bf16
        int pt = blk % 288, ct = (blk / 288) & 7, b = blk / 2304;
        int pl = t & 31, ch = t >> 5;
#pragma unroll
        for (int i = 0; i < 4; i++) {
            int cl = ch * 4 + i;
            L[cl][pl] = x[((size_t)(b * CIN + ct * 32 + cl)) * HW + pt * 32 + pl];
        }
        __syncthreads();
        int cc = t & 31;
#pragma unroll
        for (int i = 0; i < 4; i++) {
            int pr = ch * 4 + i;
            xt[((size_t)(b * HW + pt * 32 + pr)) * 256 + ct * 32 + cc] = f2bf(L[cc][pr]);
        }
    } else if (blk < 5184) {                // conv_w -> A' fragment-major bf16
        int tid = (blk - 4608) * 256 + t;   // [0,147456)
        int oc = tid / 576;
        int kc = (tid % 576) * 4;
        int k = kc >> 8, c = kc & 255;
        unsigned short v[4] __attribute__((aligned(8)));
#pragma unroll
        for (int i = 0; i < 4; i++)
            v[i] = f2bf(cw[((size_t)oc * 256 + c + i) * 9 + k]);
        int ks = kc >> 5, quad = (kc >> 3) & 3, sidx = kc & 7;
        int ifr = (oc >> 4) & 3, lane = quad * 16 + (oc & 15);
        size_t flat = (((size_t)((oc >> 6) * 72 + ks) * 4 + ifr) * 64 + lane) * 8 + sidx;
        *(uint2*)(Aw + flat) = *(const uint2*)v;
    } else {                                // off = bias, stats = 0
        int i = (blk - 5184) * 256 + t;
        if (i < 331776) off[i] = offset_b[(i / HW) % 18];
        if (i < 128) stats[i] = 0.f;
    }
}

// 3x3 pad-1 conv -> 18 offset channels (R8-proven). 16 c-chunks x 72 blocks.
__global__ __launch_bounds__(256) void offset_conv(const float* __restrict__ x,
                                                   const float* __restrict__ ow,
                                                   float* __restrict__ off) {
    int chunk = blockIdx.x / 72;
    int pg = (blockIdx.x % 72) * 256 + threadIdx.x;
    int b  = pg / HW;
    int p  = pg % HW;
    int ho = p / WID, wo = p % WID;
    const float* xb = x + (size_t)b * CIN * HW;

    float acc[18];
#pragma unroll
    for (int ch = 0; ch < 18; ch++) acc[ch] = 0.f;

    int c0 = chunk * 16;
    for (int ci = 0; ci < 16; ci++) {
        int c = c0 + ci;
        const float* xc = xb + (size_t)c * HW;
#pragma unroll
        for (int ky = 0; ky < 3; ky++) {
            int y = ho - 1 + ky;
            if (y < 0 || y >= 96) continue;
#pragma unroll
            for (int kx = 0; kx < 3; kx++) {
                int xx = wo - 1 + kx;
                float xv = (xx >= 0 && xx < 96) ? xc[y * WID + xx] : 0.f;
                int widx = c * 9 + ky * 3 + kx;
#pragma unroll
                for (int ch = 0; ch < 18; ch++)
                    acc[ch] += xv * ow[ch * (CIN * 9) + widx];
            }
        }
    }
#pragma unroll
    for (int ch = 0; ch < 18; ch++)
        atomicAdd(&off[((size_t)b * 18 + ch) * HW + p], acc[ch]);
}

// Gather (R8-proven): one wave per n, 9 taps; 4 coalesced 512B bf16 corner-row
// reads per tap; scatter-stores into B' fragment-major layout.
__global__ __launch_bounds__(256) void gather4(const unsigned short* __restrict__ xt,
                                               const float* __restrict__ off,
                                               unsigned short* __restrict__ Bp) {
    int t    = threadIdx.x;
    int w    = t >> 6;
    int lane = t & 63;
    int n    = blockIdx.x * 4 + w;
    int b    = n / HW, p = n % HW;
    int ho   = p / WID, wo = p % WID;
    const unsigned short* xb = xt + (size_t)b * (HW * 256);
    const float* offb = off + (size_t)b * 18 * HW + p;
    int c4 = lane * 4;

    int jfr = (n >> 4) & 3, l15n = n & 15;
    int lhi = lane >> 3, lq = (lane >> 1) & 3, lp = lane & 1;
    size_t gbase = (size_t)(n >> 6) * 72;

#pragma unroll 3
    for (int k = 0; k < 9; k++) {
        int ky = k / 3, kx = k % 3;
        float dy = offb[(size_t)(2 * k)     * HW];
        float dx = offb[(size_t)(2 * k + 1) * HW];
        float sy = (float)(ho - 1 + ky) + dy;
        float sx = (float)(wo - 1 + kx) + dx;
        float y0f = floorf(sy), x0f = floorf(sx);
        float fy = sy - y0f, fx = sx - x0f;
        int y0 = (int)y0f, x0 = (int)x0f;
        int y1 = y0 + 1, x1 = x0 + 1;
        float vy0 = (y0 >= 0 && y0 < 96) ? 1.f : 0.f;
        float vy1 = (y1 >= 0 && y1 < 96) ? 1.f : 0.f;
        float vx0 = (x0 >= 0 && x0 < 96) ? 1.f : 0.f;
        float vx1 = (x1 >= 0 && x1 < 96) ? 1.f : 0.f;
        int iy0 = min(max(y0, 0), 95) * WID, iy1 = min(max(y1, 0), 95) * WID;
        int ix0 = min(max(x0, 0), 95),       ix1 = min(max(x1, 0), 95);
        float w0 = (1.f - fy) * (1.f - fx) * vy0 * vx0;
        float w1 = (1.f - fy) * fx         * vy0 * vx1;
        float w2 = fy         * (1.f - fx) * vy1 * vx0;
        float w3 = fy         * fx         * vy1 * vx1;

        uint2 u0 = *(const uint2*)(xb + (size_t)(iy0 + ix0) * 256 + c4);
        uint2 u1 = *(const uint2*)(xb + (size_t)(iy0 + ix1) * 256 + c4);
        uint2 u2 = *(const uint2*)(xb + (size_t)(iy1 + ix0) * 256 + c4);
        uint2 u3 = *(const uint2*)(xb + (size_t)(iy1 + ix1) * 256 + c4);
        float r0 = w0 * bflo(u0.x) + w1 * bflo(u1.x) + w2 * bflo(u2.x) + w3 * bflo(u3.x);
        float r1 = w0 * bfhi(u0.x) + w1 * bfhi(u1.x) + w2 * bfhi(u2.x) + w3 * bfhi(u3.x);
        float r2 = w0 * bflo(u0.y) + w1 * bflo(u1.y) + w2 * bflo(u2.y) + w3 * bflo(u3.y);
        float r3 = w0 * bfhi(u0.y) + w1 * bfhi(u1.y) + w2 * bfhi(u2.y) + w3 * bfhi(u3.y);
        uint2 o;
        o.x = (unsigned)f2bf(r0) | ((unsigned)f2bf(r1) << 16);
        o.y = (unsigned)f2bf(r2) | ((unsigned)f2bf(r3) << 16);
        size_t ds = (((gbase + k * 8 + lhi) * 4 + jfr) * 64 + lq * 16 + l15n) * 8 + lp * 4;
        *(uint2*)(Bp + ds) = o;
    }
}

// Barrier-free register GEMM (R8 structure). ONE change vs R8: ring depth 4
// and __launch_bounds__(64, 1) — min 1 wave/EU lets the allocator keep the
// full ring (~210 VGPRs) live instead of collapsing it (R8 got 108 VGPRs =
// serialized loads). Grid 1152 waves = ~1.1 wave/SIMD, so the high VGPR
// count costs no achieved occupancy. Prefetch distance 3 sets.
__global__ __launch_bounds__(64, 1) void gemm_mfma(const unsigned short* __restrict__ Aw,
                                                   const unsigned short* __restrict__ Bp,
                                                   float* __restrict__ out,
                                                   float* __restrict__ stats) {
    int lane = threadIdx.x;
    int l15 = lane & 15, quad = lane >> 4;
    int f = blockIdx.x;
    int low3 = f & 7, hi = f >> 3;
    int mb = hi & 3;
    int g  = low3 + (hi >> 2) * 8;        // [0,288)

    const bf16x8* Ab = (const bf16x8*)Aw + (size_t)mb * 72 * 4 * 64 + lane;
    const bf16x8* Bb = (const bf16x8*)Bp + (size_t)g  * 72 * 4 * 64 + lane;

    f32x4 acc[4][4];
#pragma unroll
    for (int i = 0; i < 4; i++)
#pragma unroll
        for (int j = 0; j < 4; j++) acc[i][j] = (f32x4)0.f;

    bf16x8 a[4][4], b[4][4];

#define LOADSET(s, ks)                                        \
    {                                                         \
        _Pragma("unroll")                                     \
        for (int q = 0; q < 4; q++) {                         \
            a[s][q] = Ab[((ks) * 4 + q) * 64];                \
            b[s][q] = Bb[((ks) * 4 + q) * 64];                \
        }                                                     \
    }
#define MFMASET(s)                                                            \
    {                                                                         \
        _Pragma("unroll")                                                     \
        for (int i = 0; i < 4; i++)                                           \
            _Pragma("unroll")                                                 \
            for (int j = 0; j < 4; j++)                                       \
                acc[i][j] = __builtin_amdgcn_mfma_f32_16x16x32_bf16(          \
                    a[s][i], b[s][j], acc[i][j], 0, 0, 0);                    \
    }

    LOADSET(0, 0); LOADSET(1, 1); LOADSET(2, 2); LOADSET(3, 3);
    for (int ks = 0; ks < 68; ks += 4) {      // 17 iters, MFMA ks..ks+3
        MFMASET(0); LOADSET(0, ks + 4);
        MFMASET(1); LOADSET(1, ks + 5);
        MFMASET(2); LOADSET(2, ks + 6);
        MFMASET(3); LOADSET(3, ks + 7);
    }
    MFMASET(0);     // ks 68
    MFMASET(1);     // ks 69
    MFMASET(2);     // ks 70
    MFMASET(3);     // ks 71

    int b_ = g / 144;
    int p0 = (g % 144) * 64;
    float s[4] = {0.f, 0.f, 0.f, 0.f}, ss[4] = {0.f, 0.f, 0.f, 0.f};
#pragma unroll
    for (int i = 0; i < 4; i++) {
        int mr = mb * 64 + i * 16 + quad * 4;
#pragma unroll
        for (int j = 0; j < 4; j++) {
            float* ob = out + ((size_t)b_ * COUT + mr) * HW + p0 + j * 16 + l15;
#pragma unroll
            for (int r = 0; r < 4; r++) {
                float v = acc[i][j][r];
                ob[(size_t)r * HW] = v;
                s[i]  += v;
                ss[i] += v * v;
            }
        }
    }
#pragma unroll
    for (int i = 0; i < 4; i++) {
        float sv = s[i], ssv = ss[i];
#pragma unroll
        for (int d = 1; d < 32; d <<= 1) {
            sv  += __shfl_xor(sv,  d);
            ssv += __shfl_xor(ssv, d);
        }
        if ((lane & 31) == 0) {
            int bg = b_ * 32 + mb * 8 + i * 2 + (lane >> 5);
            atomicAdd(&stats[bg * 2],     sv);
            atomicAdd(&stats[bg * 2 + 1], ssv);
        }
    }
}

__global__ __launch_bounds__(256) void gn_norm(float* __restrict__ out,
                                               const float* __restrict__ stats,
                                               const float* __restrict__ gamma,
                                               const float* __restrict__ beta) {
    int i4 = blockIdx.x * 256 + threadIdx.x;
    if (i4 >= 1179648) return;
    float4 v = ((const float4*)out)[i4];
    int e  = i4 * 4;
    int ch = (e / HW) & 255;
    int b  = e / (HW * 256);
    int bg = b * 32 + (ch >> 3);
    float s = stats[bg * 2], ss = stats[bg * 2 + 1];
    float mean = s * (1.f / 73728.f);
    float rs   = rsqrtf(ss * (1.f / 73728.f) - mean * mean + 1e-5f);
    float ga = gamma[ch] * rs;
    float be = beta[ch] - mean * ga;
    v.x = fmaxf(v.x * ga + be, 0.f);
    v.y = fmaxf(v.y * ga + be, 0.f);
    v.z = fmaxf(v.z * ga + be, 0.f);
    v.w = fmaxf(v.w * ga + be, 0.f);
    ((float4*)out)[i4] = v;
}

extern "C" void kernel_launch(void* const* d_in, const int* in_sizes, int n_in,
                              void* d_out, int out_size, void* d_ws, size_t ws_size,
                              hipStream_t stream) {
    const float* x        = (const float*)d_in[0];
    const float* offset_w = (const float*)d_in[1];
    const float* offset_b = (const float*)d_in[2];
    const float* conv_w   = (const float*)d_in[3];
    const float* gamma    = (const float*)d_in[4];
    const float* beta     = (const float*)d_in[5];
    float* out = (float*)d_out;
    float* ws  = (float*)d_ws;

    float*          off   = ws;
    float*          stats = ws + 331776;
    unsigned short* Aw    = (unsigned short*)(ws + 331904);
    unsigned short* xt    = (unsigned short*)(ws + 626816);
    unsigned short* Bp    = (unsigned short*)(ws + 2986112);

    hipLaunchKernelGGL(prelude,     dim3(6480), dim3(256), 0, stream,
                       x, xt, conv_w, Aw, offset_b, off, stats);
    hipLaunchKernelGGL(offset_conv, dim3(1152), dim3(256), 0, stream, x, offset_w, off);
    hipLaunchKernelGGL(gather4,     dim3(4608), dim3(256), 0, stream, xt, off, Bp);
    hipLaunchKernelGGL(gemm_mfma,   dim3(1152), dim3(64),  0, stream, Aw, Bp, out, stats);
    hipLaunchKernelGGL(gn_norm,     dim3(4608), dim3(256), 0, stream, out, stats, gamma, beta);
}